// Round 1
// baseline (234.542 us; speedup 1.0000x reference)
//
#include <hip/hip_runtime.h>
#include <hip/hip_bf16.h>
#include <math.h>

typedef __attribute__((ext_vector_type(8))) short bf16x8;
typedef __attribute__((ext_vector_type(4))) short s16x4;
typedef __attribute__((ext_vector_type(4))) float f32x4;

constexpr int cB = 2, cS = 2048, cH = 16, cD = 64, cIn = 1024, cM = 1024;
constexpr float cLog2e = 1.4426950408889634f;

union BfPack { bf16x8 v; short s[8]; };
union BfPack4 { s16x4 v; short s[4]; };

__device__ __forceinline__ short f2bf(float f) {
    union { float f; unsigned u; } v; v.f = f;
    unsigned r = v.u + 0x7fffu + ((v.u >> 16) & 1u);   // round-to-nearest-even
    return (short)(r >> 16);
}

__device__ __forceinline__ f32x4 mfma16(bf16x8 a, bf16x8 b, f32x4 c) {
    return __builtin_amdgcn_mfma_f32_16x16x32_bf16(a, b, c, 0, 0, 0);
}

__device__ __forceinline__ void async16(const short* g, short* l) {
    __builtin_amdgcn_global_load_lds(
        (const __attribute__((address_space(1))) unsigned*)(uintptr_t)g,
        (__attribute__((address_space(3))) unsigned*)(uintptr_t)l, 16, 0, 0);
}

// ---------------------------------------------------------------------------
// Kernel 1: bias table bt[h][2048+delta] PRE-SCALED by log2(e) (for exp2),
// plus maskadd[b][key] (huge negative where masked; exp2 -> 0).
// ---------------------------------------------------------------------------
__global__ void bias_table_kernel(const float* __restrict__ rel_bias,
                                  const int* __restrict__ mask,
                                  float* __restrict__ bt,
                                  float* __restrict__ maskadd) {
    int idx = blockIdx.x * blockDim.x + threadIdx.x;
    if (idx < 4096) maskadd[idx] = (1.0f - (float)mask[idx]) * -3.0e38f;
    if (idx >= 4095) return;
    int delta = idx - 2047;
    int rb = (delta > 0) ? 16 : 0;
    int ar = delta < 0 ? -delta : delta;
    int bucket;
    if (ar < 8) {
        bucket = rb + ar;
    } else {
        float rl = 8.0f + logf((float)ar * 0.125f) * 2.8853900817779268f;
        rl = fminf(rl, 15.0f);
        bucket = rb + (int)rl;
    }
    #pragma unroll
    for (int h = 0; h < cH; h++)
        bt[h * 4096 + 2048 + delta] = rel_bias[bucket * cH + h] * cLog2e;
}

// ---------------------------------------------------------------------------
// Kernel 2a: hidden fp32 -> bf16, flat.
// ---------------------------------------------------------------------------
__global__ __launch_bounds__(256) void conv_hidden_kernel(
    const float* __restrict__ h, short* __restrict__ hbf) {
    int t = blockIdx.x * 256 + threadIdx.x;
    const float4* src = (const float4*)h;
    float4 a = src[2 * t], b = src[2 * t + 1];
    BfPack p;
    p.s[0] = f2bf(a.x); p.s[1] = f2bf(a.y); p.s[2] = f2bf(a.z); p.s[3] = f2bf(a.w);
    p.s[4] = f2bf(b.x); p.s[5] = f2bf(b.y); p.s[6] = f2bf(b.z); p.s[7] = f2bf(b.w);
    ((bf16x8*)hbf)[t] = p.v;
}

// ---------------------------------------------------------------------------
// Kernel 2b: weights fp32 [K][N] -> bf16 TRANSPOSED Wt[z][N][K].
// Wq carries 0.125 * log2(e) (softmax via exp2).
// ---------------------------------------------------------------------------
__global__ __launch_bounds__(256) void conv_wt_kernel(
    const float* __restrict__ Wq, const float* __restrict__ Wk,
    const float* __restrict__ Wv, const float* __restrict__ Wo,
    short* __restrict__ Wt) {
    const int z = blockIdx.z;
    const float* W = (z == 0) ? Wq : (z == 1) ? Wk : (z == 2) ? Wv : Wo;
    const float scale = (z == 0) ? 0.125f * cLog2e : 1.0f;
    const int n0 = blockIdx.x * 64, k0 = blockIdx.y * 64;
    __shared__ short sW[64][72];     // [k][n]
    const int t = threadIdx.x;
    const int r = t >> 2, c4 = (t & 3) * 16;
    {
        const float* src = W + (size_t)(k0 + r) * cM + n0 + c4;
        BfPack p[2];
        #pragma unroll
        for (int q = 0; q < 2; q++) {
            float4 x = ((const float4*)src)[2 * q];
            float4 y = ((const float4*)src)[2 * q + 1];
            p[q].s[0] = f2bf(x.x * scale); p[q].s[1] = f2bf(x.y * scale);
            p[q].s[2] = f2bf(x.z * scale); p[q].s[3] = f2bf(x.w * scale);
            p[q].s[4] = f2bf(y.x * scale); p[q].s[5] = f2bf(y.y * scale);
            p[q].s[6] = f2bf(y.z * scale); p[q].s[7] = f2bf(y.w * scale);
        }
        *(bf16x8*)&sW[r][c4] = p[0].v;
        *(bf16x8*)&sW[r][c4 + 8] = p[1].v;
    }
    __syncthreads();
    const int n = t >> 2, kc = (t & 3) * 16;
    BfPack o0, o1;
    #pragma unroll
    for (int j = 0; j < 8; j++) o0.s[j] = sW[kc + j][n];
    #pragma unroll
    for (int j = 0; j < 8; j++) o1.s[j] = sW[kc + 8 + j][n];
    short* dst = Wt + (size_t)z * cM * cIn + (size_t)(n0 + n) * cIn + k0 + kc;
    *(bf16x8*)dst = o0.v;
    *(bf16x8*)(dst + 8) = o1.v;
}

// ---------------------------------------------------------------------------
// GEMM core (m97-style): A[128][32], B[128][32] via global_load_lds.
// ---------------------------------------------------------------------------
template <bool SWAP>
__device__ __forceinline__ void gemm_core(
    const short* __restrict__ A, const short* __restrict__ Bt,
    short* smem, int m0, int c0, int tid, f32x4 (&acc)[4][4]) {
    short* sA = smem;
    short* sB = smem + 4096;
    const int w = tid >> 6, l = tid & 63;
    const int m16 = l & 15, g = l >> 4;
    const int srow = l >> 2, scol = (l & 3) * 8;
    const int mq = (w & 1) * 64, nq = (w >> 1) * 64;

    for (int k0 = 0; k0 < cIn; k0 += 32) {
        __syncthreads();
        async16(A + (size_t)(m0 + w * 16 + srow) * cIn + k0 + scol,
                sA + w * 512 + l * 8);
        async16(A + (size_t)(m0 + 64 + w * 16 + srow) * cIn + k0 + scol,
                sA + 2048 + w * 512 + l * 8);
        async16(Bt + (size_t)(c0 + w * 16 + srow) * cIn + k0 + scol,
                sB + w * 512 + l * 8);
        async16(Bt + (size_t)(c0 + 64 + w * 16 + srow) * cIn + k0 + scol,
                sB + 2048 + w * 512 + l * 8);
        __syncthreads();
        bf16x8 af[4], bf[4];
        #pragma unroll
        for (int i = 0; i < 4; i++)
            af[i] = *(const bf16x8*)(sA + (mq + i * 16 + m16) * 32 + g * 8);
        #pragma unroll
        for (int j = 0; j < 4; j++)
            bf[j] = *(const bf16x8*)(sB + (nq + j * 16 + m16) * 32 + g * 8);
        #pragma unroll
        for (int i = 0; i < 4; i++)
            #pragma unroll
            for (int j = 0; j < 4; j++)
                acc[i][j] = SWAP ? mfma16(bf[j], af[i], acc[i][j])
                                 : mfma16(af[i], bf[j], acc[i][j]);
    }
}

// ---------------------------------------------------------------------------
// Kernel 3: QKV GEMM. z=0 Q row-major (log2e-scaled), z=1 K row-major,
// z=2 V^T [b][h][d][kappa-col] (kappa = per-64-tile bit-permuted key index
// matching the attn PV fragment layout, so attn can stage V with
// global_load_lds and zero repack).
// ---------------------------------------------------------------------------
__global__ __launch_bounds__(256) void gemm_qkv_kernel(
    const short* __restrict__ hbf, const short* __restrict__ Wt,
    short* __restrict__ Qrm, short* __restrict__ Krm, short* __restrict__ VT) {
    const int z = blockIdx.z;
    const short* Bt = Wt + (size_t)z * cM * cIn;
    const int m0 = blockIdx.y * 128, c0 = blockIdx.x * 128;
    __shared__ short smem[8192];
    const int tid = threadIdx.x, w = tid >> 6, l = tid & 63;
    const int m16 = l & 15, g = l >> 4;
    const int mq = (w & 1) * 64, nq = (w >> 1) * 64;
    f32x4 acc[4][4] = {};

    if (z <= 1) {
        gemm_core<false>(hbf, Bt, smem, m0, c0, tid, acc);
        short* dst = (z == 0) ? Qrm : Krm;
        #pragma unroll
        for (int i = 0; i < 4; i++)
            #pragma unroll
            for (int j = 0; j < 4; j++)
                #pragma unroll
                for (int r = 0; r < 4; r++)
                    dst[(size_t)(m0 + mq + i * 16 + g * 4 + r) * cM +
                        c0 + nq + j * 16 + m16] = f2bf(acc[i][j][r]);
    } else {
        gemm_core<true>(hbf, Bt, smem, m0, c0, tid, acc);
        #pragma unroll
        for (int i = 0; i < 4; i++) {
            const int srow_g = m0 + mq + i * 16 + m16;   // b*S + s
            const int bb = srow_g >> 11, ss = srow_g & 2047;
            // kappa: bit-permute key-within-tile (b5..b0 -> b4 b3 b2 b5 b1 b0)
            const int s6 = ss & 63;
            const int kap = (s6 & 3) | ((s6 & 28) << 1) | ((s6 >> 3) & 4);
            const int col = (ss & ~63) + kap;
            #pragma unroll
            for (int j = 0; j < 4; j++)
                #pragma unroll
                for (int r = 0; r < 4; r++) {
                    const int wcol = c0 + nq + j * 16 + g * 4 + r;  // h*64+d
                    VT[(((size_t)bb * cH + (wcol >> 6)) * cD + (wcol & 63)) * cS
                       + col] = f2bf(acc[i][j][r]);
                }
        }
    }
}

// ---------------------------------------------------------------------------
// Kernel 4: flash attention (T3 2-phase structure).
// - K/V staged via global_load_lds into double-buffered linear LDS tiles
//   (no ds_write, no repack VALU, no register round-trip)
// - both-sides XOR-unit swizzle: per-lane SOURCE address carries
//   u ^= (row&7); reads carry the same involution (hoisted, free).
//   Kills the 16-way bank conflict of a linear [64][64] tile.
// - ONE barrier per tile: stage(next) issued before compute(cur);
//   __syncthreads() drains vmcnt afterward.
// - bias+mask folded into MFMA acc-init; exp2 (log2e prefolded into Q & bias)
// - lsum via ones-MFMA (matrix pipe), no end shuffle
// ---------------------------------------------------------------------------
__global__ __launch_bounds__(256) void attn_kernel(
    const short* __restrict__ Qrm, const short* __restrict__ Krm,
    const short* __restrict__ VTK, const float* __restrict__ maskadd,
    const float* __restrict__ bias_t, short* __restrict__ ctx) {
    const int b = blockIdx.z, h = blockIdx.y;
    const int q0 = blockIdx.x * 64;
    const short* VTp = VTK + ((size_t)b * cH + h) * cS * cD;   // [d][kappa-col]
    const float* bh = bias_t + h * 4096 + 2048;
    const float* mp = maskadd + b * cS;

    const int tid = threadIdx.x;
    const int wave = tid >> 6, lane = tid & 63;
    const int m16 = lane & 15, g = lane >> 4;

    __shared__ short Kt[2][64][64];    // [buf][key][d-units, XOR-swizzled]
    __shared__ short Vt[2][64][64];    // [buf][d][kappa-units, XOR-swizzled]

    const int q = q0 + wave * 16 + m16;          // this thread's q row
    const short* qb = Qrm + (size_t)(b * cS + q) * cM + h * cD;
    bf16x8 qf0 = *(const bf16x8*)(qb + g * 8);
    bf16x8 qf1 = *(const bf16x8*)(qb + 32 + g * 8);

    f32x4 o[4] = {};
    f32x4 lacc = {};
    BfPack ones;
    #pragma unroll
    for (int i = 0; i < 8; i++) ones.s[i] = (short)0x3F80;   // bf16 1.0

    // staging geometry: per thread 2 async16 per array per tile.
    // LDS slot (linear): row = wave*8 + (lane>>3) (+32 for 2nd), u = lane&7.
    const int row0 = wave * 8 + (lane >> 3);
    const int row1 = row0 + 32;
    const int u = lane & 7;
    const short* kbase = Krm + (size_t)b * cS * cM + h * cD;
    const short* srcK0 = kbase + (size_t)row0 * cM + ((u ^ (row0 & 7)) << 3);
    const short* srcK1 = kbase + (size_t)row1 * cM + ((u ^ (row1 & 7)) << 3);
    const short* srcV0 = VTp + (size_t)row0 * cS + ((u ^ (row0 & 7)) << 3);
    const short* srcV1 = VTp + (size_t)row1 * cS + ((u ^ (row1 & 7)) << 3);
    short* dK0 = (short*)Kt + wave * 512 + lane * 8;
    short* dV0 = (short*)Vt + wave * 512 + lane * 8;

    // compute-side read offset (shorts): row m16, 16B-unit (g ^ (m16&7));
    // the hi half (unit +4) is koff ^ 32.
    const int koff = m16 * 64 + ((g ^ (m16 & 7)) << 3);

    // prologue: tile 0 -> buffer 0
    async16(srcK0, dK0);
    async16(srcK1, dK0 + 2048);
    async16(srcV0, dV0);
    async16(srcV1, dV0 + 2048);
    __syncthreads();

    for (int kt = 0; kt < cS; kt += 64) {
        const int cur = (kt >> 6) & 1, nxt = cur ^ 1;
        if (kt + 64 < cS) {          // stage next tile (uniform branch)
            async16(srcK0 + (size_t)(kt + 64) * cM, dK0 + nxt * 4096);
            async16(srcK1 + (size_t)(kt + 64) * cM, dK0 + nxt * 4096 + 2048);
            async16(srcV0 + kt + 64, dV0 + nxt * 4096);
            async16(srcV1 + kt + 64, dV0 + nxt * 4096 + 2048);
        }
        const short* KtC = (const short*)Kt + cur * 4096;
        const short* VtC = (const short*)Vt + cur * 4096;

        // ---- S^T with bias+mask pre-loaded into the accumulator
        f32x4 s[4];
        #pragma unroll
        for (int st = 0; st < 4; st++) {
            const int keyb = kt + st * 16 + g * 4;
            f32x4 init;
            #pragma unroll
            for (int c = 0; c < 4; c++)
                init[c] = bh[keyb + c - q] + mp[keyb + c];
            bf16x8 klo = *(const bf16x8*)(KtC + st * 1024 + koff);
            bf16x8 khi = *(const bf16x8*)(KtC + st * 1024 + (koff ^ 32));
            s[st] = mfma16(khi, qf1, mfma16(klo, qf0, init));
        }

        // ---- softmax numerator (exp2), pack P fragments in registers
        BfPack pp[2];
        #pragma unroll
        for (int st = 0; st < 4; st++) {
            #pragma unroll
            for (int r = 0; r < 2; r++) {
                float p0 = __builtin_amdgcn_exp2f(s[st][2 * r]);
                float p1 = __builtin_amdgcn_exp2f(s[st][2 * r + 1]);
                __hip_bfloat162 h2 = __float22bfloat162_rn(float2{p0, p1});
                short2 sp = *(short2*)&h2;
                pp[st & 1].s[(st >> 1) * 4 + 2 * r]     = sp.x;
                pp[st & 1].s[(st >> 1) * 4 + 2 * r + 1] = sp.y;
            }
        }

        // ---- denominator on the matrix pipe: lacc += 1 * P
        lacc = mfma16(ones.v, pp[0].v, lacc);
        lacc = mfma16(ones.v, pp[1].v, lacc);

        // ---- O^T = V^T @ P
        #pragma unroll
        for (int nt = 0; nt < 4; nt++) {
            bf16x8 vlo = *(const bf16x8*)(VtC + nt * 1024 + koff);
            bf16x8 vhi = *(const bf16x8*)(VtC + nt * 1024 + (koff ^ 32));
            o[nt] = mfma16(vlo, pp[0].v, o[nt]);
            o[nt] = mfma16(vhi, pp[1].v, o[nt]);
        }

        __syncthreads();   // drains this wave's staging vmcnt + read fences
    }

    const float inv = 1.0f / lacc[0];    // all 4 regs identical (ones rows)
    short* cb = ctx + ((size_t)b * cS + q) * cM + h * cD;
    #pragma unroll
    for (int nt = 0; nt < 4; nt++) {
        BfPack4 pk;
        #pragma unroll
        for (int r = 0; r < 4; r++) pk.s[r] = f2bf(o[nt][r] * inv);
        *(s16x4*)(cb + nt * 16 + g * 4) = pk.v;
    }
}

// ---------------------------------------------------------------------------
// Kernel 5: out fp32 = ctx(bf16) @ WoT
// ---------------------------------------------------------------------------
__global__ __launch_bounds__(256) void gemm_o_kernel(
    const short* __restrict__ ctx, const short* __restrict__ WoT,
    float* __restrict__ out) {
    const int m0 = blockIdx.y * 128, c0 = blockIdx.x * 128;
    __shared__ short smem[8192];
    const int tid = threadIdx.x, w = tid >> 6, l = tid & 63;
    const int m16 = l & 15, g = l >> 4;
    const int mq = (w & 1) * 64, nq = (w >> 1) * 64;
    f32x4 acc[4][4] = {};
    gemm_core<false>(ctx, WoT, smem, m0, c0, tid, acc);
    #pragma unroll
    for (int i = 0; i < 4; i++)
        #pragma unroll
        for (int j = 0; j < 4; j++)
            #pragma unroll
            for (int r = 0; r < 4; r++)
                out[(size_t)(m0 + mq + i * 16 + g * 4 + r) * cM +
                    c0 + nq + j * 16 + m16] = acc[i][j][r];
}

extern "C" void kernel_launch(void* const* d_in, const int* in_sizes, int n_in,
                              void* d_out, int out_size, void* d_ws, size_t ws_size,
                              hipStream_t stream) {
    const float* hidden   = (const float*)d_in[0];
    const int*   mask     = (const int*)d_in[1];
    const float* Wq       = (const float*)d_in[2];
    const float* Wk       = (const float*)d_in[3];
    const float* Wv       = (const float*)d_in[4];
    const float* Wo       = (const float*)d_in[5];
    const float* rel_bias = (const float*)d_in[6];
    float* out = (float*)d_out;

    // ws (shorts): hbf/ctx 4M | Wt 4x1M | Q 4M | K 4M | VT 4M | bias 256KB | mask 16KB
    short* hbf_ctx = (short*)d_ws;
    short* Wt  = hbf_ctx + (size_t)4 * 1024 * 1024;
    short* Qrm = Wt  + (size_t)4 * 1024 * 1024;
    short* Krm = Qrm + (size_t)4 * 1024 * 1024;
    short* VT  = Krm + (size_t)4 * 1024 * 1024;
    float* bias_t  = (float*)(VT + (size_t)4 * 1024 * 1024);
    float* maskf   = bias_t + 16 * 4096;

    bias_table_kernel<<<16, 256, 0, stream>>>(rel_bias, mask, bias_t, maskf);
    conv_hidden_kernel<<<2048, 256, 0, stream>>>(hidden, hbf_ctx);
    conv_wt_kernel<<<dim3(16, 16, 4), 256, 0, stream>>>(Wq, Wk, Wv, Wo, Wt);
    gemm_qkv_kernel<<<dim3(8, 32, 3), 256, 0, stream>>>(hbf_ctx, Wt, Qrm, Krm, VT);
    attn_kernel<<<dim3(32, cH, cB), 256, 0, stream>>>(Qrm, Krm, VT, maskf, bias_t,
                                                      hbf_ctx);
    gemm_o_kernel<<<dim3(8, 32), 256, 0, stream>>>(hbf_ctx, Wt + (size_t)3 * 1024 * 1024,
                                                   out);
}

// Round 2
// 222.639 us; speedup vs baseline: 1.0535x; 1.0535x over previous
//
#include <hip/hip_runtime.h>
#include <hip/hip_bf16.h>
#include <math.h>

typedef __attribute__((ext_vector_type(8))) short bf16x8;
typedef __attribute__((ext_vector_type(4))) short s16x4;
typedef __attribute__((ext_vector_type(4))) float f32x4;

constexpr int cB = 2, cS = 2048, cH = 16, cD = 64, cIn = 1024, cM = 1024;
constexpr float cLog2e = 1.4426950408889634f;

union BfPack { bf16x8 v; short s[8]; };
union BfPack4 { s16x4 v; short s[4]; };

__device__ __forceinline__ short f2bf(float f) {
    union { float f; unsigned u; } v; v.f = f;
    unsigned r = v.u + 0x7fffu + ((v.u >> 16) & 1u);   // round-to-nearest-even
    return (short)(r >> 16);
}

__device__ __forceinline__ f32x4 mfma16(bf16x8 a, bf16x8 b, f32x4 c) {
    return __builtin_amdgcn_mfma_f32_16x16x32_bf16(a, b, c, 0, 0, 0);
}

__device__ __forceinline__ void async16(const short* g, short* l) {
    __builtin_amdgcn_global_load_lds(
        (const __attribute__((address_space(1))) unsigned*)(uintptr_t)g,
        (__attribute__((address_space(3))) unsigned*)(uintptr_t)l, 16, 0, 0);
}

// ---------------------------------------------------------------------------
// Kernel 1: bias table bt[h][2048+delta] PRE-SCALED by log2(e) (for exp2),
// plus maskadd[b][key] (huge negative where masked; exp2 -> 0).
// ---------------------------------------------------------------------------
__global__ void bias_table_kernel(const float* __restrict__ rel_bias,
                                  const int* __restrict__ mask,
                                  float* __restrict__ bt,
                                  float* __restrict__ maskadd) {
    int idx = blockIdx.x * blockDim.x + threadIdx.x;
    if (idx < 4096) maskadd[idx] = (1.0f - (float)mask[idx]) * -3.0e38f;
    if (idx >= 4095) return;
    int delta = idx - 2047;
    int rb = (delta > 0) ? 16 : 0;
    int ar = delta < 0 ? -delta : delta;
    int bucket;
    if (ar < 8) {
        bucket = rb + ar;
    } else {
        float rl = 8.0f + logf((float)ar * 0.125f) * 2.8853900817779268f;
        rl = fminf(rl, 15.0f);
        bucket = rb + (int)rl;
    }
    #pragma unroll
    for (int h = 0; h < cH; h++)
        bt[h * 4096 + 2048 + delta] = rel_bias[bucket * cH + h] * cLog2e;
}

// ---------------------------------------------------------------------------
// Kernel 2a: hidden fp32 -> bf16, flat.
// ---------------------------------------------------------------------------
__global__ __launch_bounds__(256) void conv_hidden_kernel(
    const float* __restrict__ h, short* __restrict__ hbf) {
    int t = blockIdx.x * 256 + threadIdx.x;
    const float4* src = (const float4*)h;
    float4 a = src[2 * t], b = src[2 * t + 1];
    BfPack p;
    p.s[0] = f2bf(a.x); p.s[1] = f2bf(a.y); p.s[2] = f2bf(a.z); p.s[3] = f2bf(a.w);
    p.s[4] = f2bf(b.x); p.s[5] = f2bf(b.y); p.s[6] = f2bf(b.z); p.s[7] = f2bf(b.w);
    ((bf16x8*)hbf)[t] = p.v;
}

// ---------------------------------------------------------------------------
// Kernel 2b: weights fp32 [K][N] -> bf16 TRANSPOSED Wt[z][N][K].
// Wq carries 0.125 * log2(e) (softmax via exp2).
// ---------------------------------------------------------------------------
__global__ __launch_bounds__(256) void conv_wt_kernel(
    const float* __restrict__ Wq, const float* __restrict__ Wk,
    const float* __restrict__ Wv, const float* __restrict__ Wo,
    short* __restrict__ Wt) {
    const int z = blockIdx.z;
    const float* W = (z == 0) ? Wq : (z == 1) ? Wk : (z == 2) ? Wv : Wo;
    const float scale = (z == 0) ? 0.125f * cLog2e : 1.0f;
    const int n0 = blockIdx.x * 64, k0 = blockIdx.y * 64;
    __shared__ short sW[64][72];     // [k][n]
    const int t = threadIdx.x;
    const int r = t >> 2, c4 = (t & 3) * 16;
    {
        const float* src = W + (size_t)(k0 + r) * cM + n0 + c4;
        BfPack p[2];
        #pragma unroll
        for (int q = 0; q < 2; q++) {
            float4 x = ((const float4*)src)[2 * q];
            float4 y = ((const float4*)src)[2 * q + 1];
            p[q].s[0] = f2bf(x.x * scale); p[q].s[1] = f2bf(x.y * scale);
            p[q].s[2] = f2bf(x.z * scale); p[q].s[3] = f2bf(x.w * scale);
            p[q].s[4] = f2bf(y.x * scale); p[q].s[5] = f2bf(y.y * scale);
            p[q].s[6] = f2bf(y.z * scale); p[q].s[7] = f2bf(y.w * scale);
        }
        *(bf16x8*)&sW[r][c4] = p[0].v;
        *(bf16x8*)&sW[r][c4 + 8] = p[1].v;
    }
    __syncthreads();
    const int n = t >> 2, kc = (t & 3) * 16;
    BfPack o0, o1;
    #pragma unroll
    for (int j = 0; j < 8; j++) o0.s[j] = sW[kc + j][n];
    #pragma unroll
    for (int j = 0; j < 8; j++) o1.s[j] = sW[kc + 8 + j][n];
    short* dst = Wt + (size_t)z * cM * cIn + (size_t)(n0 + n) * cIn + k0 + kc;
    *(bf16x8*)dst = o0.v;
    *(bf16x8*)(dst + 8) = o1.v;
}

// ---------------------------------------------------------------------------
// GEMM core (m97-style): A[128][32], B[128][32] via global_load_lds.
// ---------------------------------------------------------------------------
template <bool SWAP>
__device__ __forceinline__ void gemm_core(
    const short* __restrict__ A, const short* __restrict__ Bt,
    short* smem, int m0, int c0, int tid, f32x4 (&acc)[4][4]) {
    short* sA = smem;
    short* sB = smem + 4096;
    const int w = tid >> 6, l = tid & 63;
    const int m16 = l & 15, g = l >> 4;
    const int srow = l >> 2, scol = (l & 3) * 8;
    const int mq = (w & 1) * 64, nq = (w >> 1) * 64;

    for (int k0 = 0; k0 < cIn; k0 += 32) {
        __syncthreads();
        async16(A + (size_t)(m0 + w * 16 + srow) * cIn + k0 + scol,
                sA + w * 512 + l * 8);
        async16(A + (size_t)(m0 + 64 + w * 16 + srow) * cIn + k0 + scol,
                sA + 2048 + w * 512 + l * 8);
        async16(Bt + (size_t)(c0 + w * 16 + srow) * cIn + k0 + scol,
                sB + w * 512 + l * 8);
        async16(Bt + (size_t)(c0 + 64 + w * 16 + srow) * cIn + k0 + scol,
                sB + 2048 + w * 512 + l * 8);
        __syncthreads();
        bf16x8 af[4], bf[4];
        #pragma unroll
        for (int i = 0; i < 4; i++)
            af[i] = *(const bf16x8*)(sA + (mq + i * 16 + m16) * 32 + g * 8);
        #pragma unroll
        for (int j = 0; j < 4; j++)
            bf[j] = *(const bf16x8*)(sB + (nq + j * 16 + m16) * 32 + g * 8);
        #pragma unroll
        for (int i = 0; i < 4; i++)
            #pragma unroll
            for (int j = 0; j < 4; j++)
                acc[i][j] = SWAP ? mfma16(bf[j], af[i], acc[i][j])
                                 : mfma16(af[i], bf[j], acc[i][j]);
    }
}

// ---------------------------------------------------------------------------
// Kernel 3: QKV GEMM. z=0 Q row-major (log2e-scaled), z=1 K row-major,
// z=2 V^T [b][h][d][kappa-col] (kappa = per-64-tile bit-permuted key index
// matching the attn PV fragment layout, so attn can stage V with
// global_load_lds and zero repack).
// ---------------------------------------------------------------------------
__global__ __launch_bounds__(256) void gemm_qkv_kernel(
    const short* __restrict__ hbf, const short* __restrict__ Wt,
    short* __restrict__ Qrm, short* __restrict__ Krm, short* __restrict__ VT) {
    const int z = blockIdx.z;
    const short* Bt = Wt + (size_t)z * cM * cIn;
    const int m0 = blockIdx.y * 128, c0 = blockIdx.x * 128;
    __shared__ short smem[8192];
    const int tid = threadIdx.x, w = tid >> 6, l = tid & 63;
    const int m16 = l & 15, g = l >> 4;
    const int mq = (w & 1) * 64, nq = (w >> 1) * 64;
    f32x4 acc[4][4] = {};

    if (z <= 1) {
        gemm_core<false>(hbf, Bt, smem, m0, c0, tid, acc);
        short* dst = (z == 0) ? Qrm : Krm;
        #pragma unroll
        for (int i = 0; i < 4; i++)
            #pragma unroll
            for (int j = 0; j < 4; j++)
                #pragma unroll
                for (int r = 0; r < 4; r++)
                    dst[(size_t)(m0 + mq + i * 16 + g * 4 + r) * cM +
                        c0 + nq + j * 16 + m16] = f2bf(acc[i][j][r]);
    } else {
        gemm_core<true>(hbf, Bt, smem, m0, c0, tid, acc);
        #pragma unroll
        for (int i = 0; i < 4; i++) {
            const int srow_g = m0 + mq + i * 16 + m16;   // b*S + s
            const int bb = srow_g >> 11, ss = srow_g & 2047;
            // kappa: bit-permute key-within-tile (b5..b0 -> b4 b3 b2 b5 b1 b0)
            const int s6 = ss & 63;
            const int kap = (s6 & 3) | ((s6 & 28) << 1) | ((s6 >> 3) & 4);
            const int col = (ss & ~63) + kap;
            #pragma unroll
            for (int j = 0; j < 4; j++)
                #pragma unroll
                for (int r = 0; r < 4; r++) {
                    const int wcol = c0 + nq + j * 16 + g * 4 + r;  // h*64+d
                    VT[(((size_t)bb * cH + (wcol >> 6)) * cD + (wcol & 63)) * cS
                       + col] = f2bf(acc[i][j][r]);
                }
        }
    }
}

// ---------------------------------------------------------------------------
// Kernel 4: flash attention, register-blocked.
// Each wave: 32 q-rows (two 16-row MFMA groups, 64 apart) x 128-key tiles.
// K/V LDS fragments are SHARED across the two q-groups -> 2x arithmetic
// intensity per LDS/bias access; 128-key tile -> one barrier per 128 keys.
// K/V staged via global_load_lds (linear dst) with XOR-unit swizzle applied
// to the per-lane GLOBAL source and to the LDS read (both-sides involution).
// LDS: K[2][128][64] + V[2][64][128] = 64 KB, double-buffered, 1 barrier/tile.
// ---------------------------------------------------------------------------
__global__ __launch_bounds__(256, 2) void attn_kernel(
    const short* __restrict__ Qrm, const short* __restrict__ Krm,
    const short* __restrict__ VTK, const float* __restrict__ maskadd,
    const float* __restrict__ bias_t, short* __restrict__ ctx) {
    const int b = blockIdx.z, h = blockIdx.y;
    const int q0 = blockIdx.x * 128;
    const short* VTp = VTK + ((size_t)b * cH + h) * cS * cD;   // [d][kappa-col]
    const float* bh = bias_t + h * 4096 + 2048;
    const float* mp = maskadd + b * cS;

    const int tid = threadIdx.x;
    const int wave = tid >> 6, lane = tid & 63;
    const int m16 = lane & 15, g = lane >> 4;

    __shared__ short Kt[2][128 * 64];    // [buf][key][d-unit swz]   32 KB
    __shared__ short Vt[2][64 * 128];    // [buf][d][kappa-unit swz] 32 KB

    // ---- Q fragments for the two q-groups (64 rows apart)
    int qv[2];
    bf16x8 qf[2][2];
    #pragma unroll
    for (int qq = 0; qq < 2; qq++) {
        qv[qq] = q0 + qq * 64 + wave * 16 + m16;
        const short* qb = Qrm + (size_t)(b * cS + qv[qq]) * cM + h * cD;
        qf[qq][0] = *(const bf16x8*)(qb + g * 8);
        qf[qq][1] = *(const bf16x8*)(qb + 32 + g * 8);
    }

    f32x4 o[2][4] = {};
    f32x4 lacc[2] = {};
    BfPack ones;
    #pragma unroll
    for (int i = 0; i < 8; i++) ones.s[i] = (short)0x3F80;   // bf16 1.0

    // ---- staging geometry (8 async16 per thread per 128-key tile)
    // K: rows r8 + c*32 (c=0..3), 8 units of 16B per 128B row
    // V: rows r16 + c*16, 16 units of 16B per 256B row
    const int u8 = tid & 7, r8 = tid >> 3;
    const int u16s = tid & 15, r16 = tid >> 4;
    const short* pK = Krm + ((size_t)b * cS + r8) * cM + h * cD +
                      ((u8 ^ (r8 & 7)) << 3);
    const short* pV = VTp + (size_t)r16 * cS + ((u16s ^ (r16 & 7)) << 3);
    short* dK = (short*)Kt + tid * 8;
    short* dV = (short*)Vt + tid * 8;

    // ---- compute-side swizzled unit offsets (shorts)
    const int kx0 = ((g ^ (m16 & 7)) << 3);          // lo 16B unit
    const int kx1 = (((g + 4) ^ (m16 & 7)) << 3);    // hi 16B unit

    // ---- prologue: tile 0 -> buffer 0
    #pragma unroll
    for (int c = 0; c < 4; c++) {
        async16(pK + (size_t)(c * 32) * cM, dK + c * 2048);
        async16(pV + (size_t)(c * 16) * cS, dV + c * 2048);
    }
    __syncthreads();

    for (int kt = 0; kt < cS; kt += 128) {
        const int buf = (kt >> 7) & 1, nxt = buf ^ 1;
        if (kt + 128 < cS) {           // stage next tile (uniform branch)
            #pragma unroll
            for (int c = 0; c < 4; c++) {
                async16(pK + (size_t)(kt + 128 + c * 32) * cM,
                        dK + nxt * 8192 + c * 2048);
                async16(pV + (size_t)(c * 16) * cS + kt + 128,
                        dV + nxt * 8192 + c * 2048);
            }
        }
        const short* K_ = (const short*)Kt + buf * 8192;
        const short* V_ = (const short*)Vt + buf * 8192;

        #pragma unroll
        for (int h2 = 0; h2 < 2; h2++) {
            // ---- S^T for this 64-key half, both q-groups (K frags shared)
            f32x4 s[2][4];
            __builtin_amdgcn_s_setprio(1);
            #pragma unroll
            for (int t4 = 0; t4 < 4; t4++) {
                const int st = h2 * 4 + t4;
                const int keyb = kt + st * 16 + g * 4;
                bf16x8 klo = *(const bf16x8*)(K_ + (st * 16 + m16) * 64 + kx0);
                bf16x8 khi = *(const bf16x8*)(K_ + (st * 16 + m16) * 64 + kx1);
                #pragma unroll
                for (int qq = 0; qq < 2; qq++) {
                    f32x4 init;
                    #pragma unroll
                    for (int c = 0; c < 4; c++)
                        init[c] = bh[keyb + c - qv[qq]] + mp[keyb + c];
                    s[qq][t4] = mfma16(khi, qf[qq][1],
                                       mfma16(klo, qf[qq][0], init));
                }
            }
            __builtin_amdgcn_s_setprio(0);

            // ---- softmax numerator (exp2), pack P fragments
            BfPack pp[2][2];
            #pragma unroll
            for (int qq = 0; qq < 2; qq++)
                #pragma unroll
                for (int t4 = 0; t4 < 4; t4++)
                    #pragma unroll
                    for (int r = 0; r < 2; r++) {
                        float p0 = __builtin_amdgcn_exp2f(s[qq][t4][2 * r]);
                        float p1 = __builtin_amdgcn_exp2f(s[qq][t4][2 * r + 1]);
                        __hip_bfloat162 h2v = __float22bfloat162_rn(float2{p0, p1});
                        short2 sp = *(short2*)&h2v;
                        pp[qq][t4 & 1].s[(t4 >> 1) * 4 + 2 * r]     = sp.x;
                        pp[qq][t4 & 1].s[(t4 >> 1) * 4 + 2 * r + 1] = sp.y;
                    }

            // ---- denominator on the matrix pipe + O^T = V^T @ P
            __builtin_amdgcn_s_setprio(1);
            #pragma unroll
            for (int qq = 0; qq < 2; qq++) {
                lacc[qq] = mfma16(ones.v, pp[qq][0].v, lacc[qq]);
                lacc[qq] = mfma16(ones.v, pp[qq][1].v, lacc[qq]);
            }
            #pragma unroll
            for (int nt = 0; nt < 4; nt++) {
                bf16x8 vlo = *(const bf16x8*)(V_ + (nt * 16 + m16) * 128 +
                                              h2 * 64 + kx0);
                bf16x8 vhi = *(const bf16x8*)(V_ + (nt * 16 + m16) * 128 +
                                              h2 * 64 + kx1);
                #pragma unroll
                for (int qq = 0; qq < 2; qq++) {
                    o[qq][nt] = mfma16(vlo, pp[qq][0].v, o[qq][nt]);
                    o[qq][nt] = mfma16(vhi, pp[qq][1].v, o[qq][nt]);
                }
            }
            __builtin_amdgcn_s_setprio(0);
        }

        __syncthreads();   // staging (nxt) complete + all reads of buf done
    }

    #pragma unroll
    for (int qq = 0; qq < 2; qq++) {
        const float inv = 1.0f / lacc[qq][0];   // all 4 regs identical
        short* cb = ctx + (size_t)(b * cS + qv[qq]) * cM + h * cD;
        #pragma unroll
        for (int nt = 0; nt < 4; nt++) {
            BfPack4 pk;
            #pragma unroll
            for (int r = 0; r < 4; r++) pk.s[r] = f2bf(o[qq][nt][r] * inv);
            *(s16x4*)(cb + nt * 16 + g * 4) = pk.v;
        }
    }
}

// ---------------------------------------------------------------------------
// Kernel 5: out fp32 = ctx(bf16) @ WoT
// ---------------------------------------------------------------------------
__global__ __launch_bounds__(256) void gemm_o_kernel(
    const short* __restrict__ ctx, const short* __restrict__ WoT,
    float* __restrict__ out) {
    const int m0 = blockIdx.y * 128, c0 = blockIdx.x * 128;
    __shared__ short smem[8192];
    const int tid = threadIdx.x, w = tid >> 6, l = tid & 63;
    const int m16 = l & 15, g = l >> 4;
    const int mq = (w & 1) * 64, nq = (w >> 1) * 64;
    f32x4 acc[4][4] = {};
    gemm_core<false>(ctx, WoT, smem, m0, c0, tid, acc);
    #pragma unroll
    for (int i = 0; i < 4; i++)
        #pragma unroll
        for (int j = 0; j < 4; j++)
            #pragma unroll
            for (int r = 0; r < 4; r++)
                out[(size_t)(m0 + mq + i * 16 + g * 4 + r) * cM +
                    c0 + nq + j * 16 + m16] = acc[i][j][r];
}

extern "C" void kernel_launch(void* const* d_in, const int* in_sizes, int n_in,
                              void* d_out, int out_size, void* d_ws, size_t ws_size,
                              hipStream_t stream) {
    const float* hidden   = (const float*)d_in[0];
    const int*   mask     = (const int*)d_in[1];
    const float* Wq       = (const float*)d_in[2];
    const float* Wk       = (const float*)d_in[3];
    const float* Wv       = (const float*)d_in[4];
    const float* Wo       = (const float*)d_in[5];
    const float* rel_bias = (const float*)d_in[6];
    float* out = (float*)d_out;

    // ws (shorts): hbf/ctx 4M | Wt 4x1M | Q 4M | K 4M | VT 4M | bias 256KB | mask 16KB
    short* hbf_ctx = (short*)d_ws;
    short* Wt  = hbf_ctx + (size_t)4 * 1024 * 1024;
    short* Qrm = Wt  + (size_t)4 * 1024 * 1024;
    short* Krm = Qrm + (size_t)4 * 1024 * 1024;
    short* VT  = Krm + (size_t)4 * 1024 * 1024;
    float* bias_t  = (float*)(VT + (size_t)4 * 1024 * 1024);
    float* maskf   = bias_t + 16 * 4096;

    bias_table_kernel<<<16, 256, 0, stream>>>(rel_bias, mask, bias_t, maskf);
    conv_hidden_kernel<<<2048, 256, 0, stream>>>(hidden, hbf_ctx);
    conv_wt_kernel<<<dim3(16, 16, 4), 256, 0, stream>>>(Wq, Wk, Wv, Wo, Wt);
    gemm_qkv_kernel<<<dim3(8, 32, 3), 256, 0, stream>>>(hbf_ctx, Wt, Qrm, Krm, VT);
    attn_kernel<<<dim3(16, cH, cB), 256, 0, stream>>>(Qrm, Krm, VT, maskf, bias_t,
                                                      hbf_ctx);
    gemm_o_kernel<<<dim3(8, 32), 256, 0, stream>>>(hbf_ctx, Wt + (size_t)3 * 1024 * 1024,
                                                   out);
}